// Round 2
// baseline (6673.447 us; speedup 1.0000x reference)
//
#include <hip/hip_runtime.h>

#define BATCH 8
#define N 32768
#define NPOINT 2048
#define NT 512               // threads per block (8 waves)
#define NW (NT / 64)
#define NG 16                // 16 groups of 4 points per thread (64 pts/thread)

typedef __attribute__((ext_vector_type(2))) float f2;
typedef __attribute__((ext_vector_type(4))) float f4;

// Packed f32 math, hand-forced (compiler scalarizes the f2 ops under
// fp contract(off)). Plain VOP3P only — no operand modifiers, maximum
// assembler compatibility. Subtraction is done as a + (-pivot) with the
// pivot negated once per iteration (bit-identical IEEE result).
// numpy evaluation order (dx*dx + dy*dy) + dz*dz preserved, no FMA.
#define PK_ADD(d,a,b) asm("v_pk_add_f32 %0, %1, %2" : "=v"(d) : "v"(a), "v"(b))
#define PK_MUL(d,a,b) asm("v_pk_mul_f32 %0, %1, %2" : "=v"(d) : "v"(a), "v"(b))
#define MAX3ACC(acc,b,c) asm("v_max3_f32 %0, %0, %1, %2" \
                             : "+v"(acc) : "v"(b), "v"(c))

#define REP16(M)  M(0)  M(1)  M(2)  M(3)  M(4)  M(5)  M(6)  M(7) \
                  M(8)  M(9)  M(10) M(11) M(12) M(13) M(14) M(15)
#define REP16R(M) M(15) M(14) M(13) M(12) M(11) M(10) M(9)  M(8) \
                  M(7)  M(6)  M(5)  M(4)  M(3)  M(2)  M(1)  M(0)

__global__ __attribute__((amdgpu_flat_work_group_size(NT, NT),
                          amdgpu_waves_per_eu(2, 2)))
void fps_kernel(const float* __restrict__ pts_t,  // (B,3,N)
                float* __restrict__ out)          // (B,3,NPOINT)
{
#pragma clang fp contract(off)
    __shared__ alignas(16) f4 s_z4[N / 4];   // 128 KiB, conflict-free b128
    __shared__ unsigned s_M[2];              // global max (float bits), dbuf
    __shared__ int s_besti[2];               // argmax index, dbuf

    const int b = blockIdx.x;
    const int t = threadIdx.x;

    const float* __restrict__ px = pts_t + (size_t)b * 3 * N;
    const float* __restrict__ py = px + N;
    const float* __restrict__ pz = py + N;
    const f4* __restrict__ px4 = (const f4*)px;
    const f4* __restrict__ py4 = (const f4*)py;
    const f4* __restrict__ pz4 = (const f4*)pz;
    float* outx = out + (size_t)b * 3 * NPOINT;
    float* outy = outx + NPOINT;
    float* outz = outy + NPOINT;

    // ---- 96 named f2 registers: x, y, temp (2 halves per 4-pt group) ----
#define DECL(g) f2 xa##g, xb##g, ya##g, yb##g, Ta##g, Tb##g;
    REP16(DECL)
#undef DECL

    // ---- load x,y into registers (f4 global loads); z into LDS; init T ----
#define LOADG(g) { const int Q = (g) * NT + t;                 \
                   f4 vx = px4[Q]; f4 vy = py4[Q];             \
                   xa##g = vx.xy;  xb##g = vx.zw;              \
                   ya##g = vy.xy;  yb##g = vy.zw;              \
                   s_z4[Q] = pz4[Q];                           \
                   Ta##g = (f2){1e10f, 1e10f};                 \
                   Tb##g = (f2){1e10f, 1e10f}; }
    REP16(LOADG)
#undef LOADG

    // First selected index is 0 (reference: idx[0] = 0).
    float lx = px[0], ly = py[0], lz = pz[0];
    if (t == 0) {
        outx[0] = lx; outy[0] = ly; outz[0] = lz;
        s_besti[0] = N; s_besti[1] = N;
        s_M[0] = 0u;    s_M[1] = 0u;
    }
    __syncthreads();

    for (int j = 1; j < NPOINT; ++j) {
        // negated pivot, broadcast to packed lanes (a + (-p) == a - p exactly)
        const float nlx = -lx, nly = -ly, nlz = -lz;
        const f2 nlx2 = (f2){nlx, nlx};
        const f2 nly2 = (f2){nly, nly};
        const f2 nlz2 = (f2){nlz, nlz};

        // --- update temps vs pivot (packed math); 4 rotating max accs ---
        float m0 = 0.0f, m1 = 0.0f, m2 = 0.0f, m3 = 0.0f;
#define ACC0(g) m0
#define ACC1(g) m1
#define ACC2(g) m2
#define ACC3(g) m3
#define UPD(g) { const int Q = (g) * NT + t;                               \
                 f4 z4 = s_z4[Q];                                          \
                 f2 dxa, dxb, dya, dyb, dza, dzb, pa, pb, qa, qb, sa, sb;  \
                 PK_ADD(dza, z4.xy, nlz2);  PK_ADD(dzb, z4.zw, nlz2);      \
                 PK_ADD(dxa, xa##g, nlx2);  PK_ADD(dxb, xb##g, nlx2);      \
                 PK_ADD(dya, ya##g, nly2);  PK_ADD(dyb, yb##g, nly2);      \
                 PK_MUL(pa, dxa, dxa);      PK_MUL(pb, dxb, dxb);          \
                 PK_MUL(qa, dya, dya);      PK_MUL(qb, dyb, dyb);          \
                 PK_ADD(qa, pa, qa);        PK_ADD(qb, pb, qb);            \
                 PK_MUL(pa, dza, dza);      PK_MUL(pb, dzb, dzb);          \
                 PK_ADD(sa, qa, pa);        PK_ADD(sb, qb, pb); /* numpy order */ \
                 Ta##g.x = fminf(Ta##g.x, sa.x);                           \
                 Ta##g.y = fminf(Ta##g.y, sa.y);                           \
                 Tb##g.x = fminf(Tb##g.x, sb.x);                           \
                 Tb##g.y = fminf(Tb##g.y, sb.y);                           \
                 if (((g) & 1) == 0) { MAX3ACC(m0, Ta##g.x, Ta##g.y);      \
                                       MAX3ACC(m1, Tb##g.x, Tb##g.y); }    \
                 else                { MAX3ACC(m2, Ta##g.x, Ta##g.y);      \
                                       MAX3ACC(m3, Tb##g.x, Tb##g.y); } }
        REP16(UPD)
#undef UPD
        float vmax = fmaxf(fmaxf(m0, m1), fmaxf(m2, m3));

        // --- wave max (all lanes end with wave max) ---
#pragma unroll
        for (int off = 32; off >= 1; off >>= 1)
            vmax = fmaxf(vmax, __shfl_xor(vmax, off));

        // --- cross-wave max via one LDS atomic per wave (bits monotone: T>=0) ---
        if ((t & 63) == 0) atomicMax(&s_M[j & 1], __float_as_uint(vmax));
        __syncthreads();                       // barrier 1

        if (t == 0) {                          // prep other slot for next iter
            s_M[(j + 1) & 1] = 0u;
            s_besti[(j + 1) & 1] = N;
        }
        const float M = __uint_as_float(s_M[j & 1]);

        // --- lazy argmax: only the wave(s) holding M rescan (registers) ---
        if (vmax == M) {                       // wave-uniform branch
            int cand = N;
#define SCANG(g) { const int base4 = 4 * ((g) * NT + t);        \
                   cand = (Tb##g.y == M) ? base4 + 3 : cand;    \
                   cand = (Tb##g.x == M) ? base4 + 2 : cand;    \
                   cand = (Ta##g.y == M) ? base4 + 1 : cand;    \
                   cand = (Ta##g.x == M) ? base4     : cand; }
            REP16R(SCANG)                      // descending -> lowest idx wins
#undef SCANG
            if (cand < N) atomicMin(&s_besti[j & 1], cand);
        }
        __syncthreads();                       // barrier 2

        const int sel = __builtin_amdgcn_readfirstlane(s_besti[j & 1]);
        lx = px[sel];                          // uniform -> scalar load (L2-hit)
        ly = py[sel];
        lz = pz[sel];
        if (t == 0) { outx[j] = lx; outy[j] = ly; outz[j] = lz; }
    }
}

extern "C" void kernel_launch(void* const* d_in, const int* in_sizes, int n_in,
                              void* d_out, int out_size, void* d_ws, size_t ws_size,
                              hipStream_t stream) {
    // d_in[0]: points_xyz (B,N,3) — unused
    // d_in[1]: points_xyz_t (B,3,N)
    // d_in[2]: features_with_xyz (B,67,N) — unused
    const float* pts_t = (const float*)d_in[1];
    float* out = (float*)d_out;
    fps_kernel<<<BATCH, NT, 0, stream>>>(pts_t, out);
}